// Round 11
// baseline (329.775 us; speedup 1.0000x reference)
//
#include <hip/hip_runtime.h>
#include <math.h>

typedef unsigned short ushort_t;
typedef __attribute__((ext_vector_type(8))) short short8;   // 8 bf16 = 4 VGPR (MFMA A/B frag)
typedef __attribute__((ext_vector_type(4))) float f32x4;    // MFMA C/D frag
typedef __attribute__((ext_vector_type(4))) int int4v;

constexpr int S = 1024, D = 64, BH = 64;
constexpr int HALF = BH * S * D;          // imag offset in output
constexpr int KROW = 72;                  // ush row stride, K tiles (rows=s, cols=d)
constexpr int VROW = 72;                  // ush row stride, interleaved V^T (rows=d, cols=k'=2s+c)
constexpr int TILE_USH = 2 * 32 * KROW + 64 * VROW;  // 4608 + 4608 = 9216 ush = 18432 B
constexpr int TILE_B = TILE_USH * 2;                 // 18432 B
constexpr size_t WS_NEED = (size_t)BH * 32 * TILE_B; // 37.7 MB (< 39.8 MB cap)

#define MFMA16(a, b, c) __builtin_amdgcn_mfma_f32_16x16x32_bf16(a, b, c, 0, 0, 0)

// ---- packed fp32->bf16 (RNE): lo=bf16(a), hi=bf16(b) ----
// R1/R5 lesson: raw `v_cvt_pk_bf16_f32` inline asm does NOT behave as a two-source
// pack on this toolchain. The __bf16-cast form is correct; never asm this.
__device__ __forceinline__ unsigned cvtpk(float a, float b) {
  __bf16 la = (__bf16)a, lb = (__bf16)b;
  unsigned short lo, hi;
  __builtin_memcpy(&lo, &la, 2);
  __builtin_memcpy(&hi, &lb, 2);
  return (unsigned)lo | ((unsigned)hi << 16);
}

__device__ __forceinline__ int4v pack8(float4 a, float4 b) {  // 8 fp32 -> 8 bf16 in 16B
  int4v r;
  r.x = (int)cvtpk(a.x, a.y);
  r.y = (int)cvtpk(a.z, a.w);
  r.z = (int)cvtpk(b.x, b.y);
  r.w = (int)cvtpk(b.z, b.w);
  return r;
}

// async global->LDS staging of one 18432 B tile (linear layout both sides).
__device__ __forceinline__ void stage_tile(const ushort_t* __restrict__ g,
                                           char* l, int t) {
#pragma unroll
  for (int i = 0; i < 5; ++i) {
    const int idx = i * 256 + t;
    if (idx < TILE_B / 16) {
      __builtin_amdgcn_global_load_lds(
          (const __attribute__((address_space(1))) unsigned*)(g) + idx * 4,
          (__attribute__((address_space(3))) unsigned*)(l) + idx * 4, 16, 0, 0);
    }
  }
}

// ---------------- prepass: K classic bf16; V^T complex-interleaved (vr,-vi) --------------
// R9 lesson: total - dispatch is a CONSTANT ~115us fixed harness overhead regardless of
// kernel count -> prepass is near its roofline. R8 version, unchanged.
__global__ __launch_bounds__(256)
void prepass_kernel(const float* __restrict__ kr, const float* __restrict__ ki,
                    const float* __restrict__ vr, const float* __restrict__ vi,
                    ushort_t* __restrict__ ws) {
  __shared__ float svr[32 * 72], svi[32 * 72];
  const int t = threadIdx.x;
  const int k = t >> 3, d0 = (t & 7) * 8;
  const int dT = t >> 2, k0 = (t & 3) * 8;

  for (int it = 0; it < 2; ++it) {
    const int tile = blockIdx.x * 2 + it;
    const size_t gbase = (size_t)tile * (32 * D);
    ushort_t* wst = ws + (size_t)tile * TILE_USH;
    {
      float4 a = *(const float4*)(kr + gbase + k * D + d0);
      float4 b = *(const float4*)(kr + gbase + k * D + d0 + 4);
      *(int4v*)(wst + k * KROW + d0) = pack8(a, b);
    }
    {
      float4 a = *(const float4*)(ki + gbase + k * D + d0);
      float4 b = *(const float4*)(ki + gbase + k * D + d0 + 4);
      *(int4v*)(wst + 2304 + k * KROW + d0) = pack8(a, b);
    }
    {
      float4 a = *(const float4*)(vr + gbase + k * D + d0);
      float4 b = *(const float4*)(vr + gbase + k * D + d0 + 4);
      *(float4*)&svr[k * 72 + d0] = a;
      *(float4*)&svr[k * 72 + d0 + 4] = b;
      float4 c = *(const float4*)(vi + gbase + k * D + d0);
      float4 d = *(const float4*)(vi + gbase + k * D + d0 + 4);
      *(float4*)&svi[k * 72 + d0] = c;
      *(float4*)&svi[k * 72 + d0 + 4] = d;
    }
    __syncthreads();
    {
      unsigned dws[8];
#pragma unroll
      for (int j = 0; j < 8; ++j) {
        int s = k0 + j;
        dws[j] = cvtpk(svr[s * 72 + dT], -svi[s * 72 + dT]);  // pair (vr, -vi)
      }
      ushort_t* dst = wst + 4608 + dT * VROW + 2 * k0;
      *(int4v*)dst = *(int4v*)&dws[0];
      *(int4v*)(dst + 8) = *(int4v*)&dws[4];
    }
    __syncthreads();
  }
}

// ---------------- main MFMA kernel: 64 q-rows/block, 4 waves, 4 blocks/CU ----------------
// Round 11 = exact R8 revert (R10's phase-batching regressed: more live state ->
// register moves, MfmaUtil down) + ONE change: QK accumulation chains split 4-deep ->
// two 2-deep partials (cS*A + cS*B). 4 independent MFMA chains instead of 2 cuts the
// dependent-MFMA bubble in the latency-bound inner loop; +16 VALU adds/iter, 2
// transient f32x4, zero layout/sync/numerics risk.
__global__ __launch_bounds__(256, 4)
void cvattn_mfma(const float* __restrict__ gq_r, const float* __restrict__ gq_i,
                 const ushort_t* __restrict__ ws, float* __restrict__ gout) {
  __shared__ __attribute__((aligned(16))) char smem[2 * 18432];
  ushort_t* sB = (ushort_t*)smem;
  const int t = threadIdx.x;
  const int lane = t & 63, wave = t >> 6;
  const int m = lane & 15, quad = lane >> 4;

  // XCD-aware block mapping: all 16 q-tiles of one bh share id%8 -> same XCD L2.
  const int id = blockIdx.x;                 // 0..1023
  const int bh = (id & 7) * 8 + ((id >> 3) & 7);
  const int qt = id >> 6;                    // 0..15 (64 q-rows each)
  const size_t base = (size_t)bh * (S * D);

  // ---- Q fragments straight from global (one-time, uncoalesced-but-small) ----
  short8 fQr[2], fQi[2], fQn[2];   // [dc]; fQn = -fQi (loop-invariant)
  {
    const int row = qt * 64 + wave * 16 + m;
#pragma unroll
    for (int dc = 0; dc < 2; ++dc) {
      const int d = dc * 32 + quad * 8;
      const float* pr = gq_r + base + (size_t)row * D + d;
      const float* pi = gq_i + base + (size_t)row * D + d;
      int4v vr_ = pack8(*(const float4*)pr, *(const float4*)(pr + 4));
      int4v vi_ = pack8(*(const float4*)pi, *(const float4*)(pi + 4));
      __builtin_memcpy(&fQr[dc], &vr_, 16);
      __builtin_memcpy(&fQi[dc], &vi_, 16);
      fQn[dc] = fQi[dc] ^ (short)0x8000;
    }
  }

  f32x4 aAr[4] = {}, aAi[4] = {}, aUr[4] = {}, aUi[4] = {};
  float mn2 = 1e30f, mx2 = 0.f;              // per-lane stats of |s|^2, q = m

  const ushort_t* wsrc = ws + (size_t)bh * 32 * TILE_USH;

  // ---- prologue: tile0 -> buf0 (async), drain at barrier ----
  stage_tile(wsrc, smem, t);
  __syncthreads();

  for (int kb = 0; kb < 32; ++kb) {
    const int cur = kb & 1;
    const int cbu = cur * 9216;        // ush offset of current buffer
    const int cbd = cur * 4608;        // dw offset

    // issue next tile's async loads first; they complete under this iter's compute
    if (kb + 1 < 32)
      stage_tile(wsrc + (size_t)(kb + 1) * TILE_USH, smem + (cur ^ 1) * 18432, t);

    // ---- swapped QK^T (mfma(K,Q)): lane(m,quad) gets S[q=m][k=ks*16+quad*4+r],
    //      which IS the PV A-frag layout -> P/U built in-lane, no LDS round-trip.
#pragma unroll
    for (int ks = 0; ks < 2; ++ks) {
      const int krow = ks * 16 + m;
      short8 fKr0 = *(const short8*)&sB[cbu + krow * KROW + quad * 8];
      short8 fKr1 = *(const short8*)&sB[cbu + krow * KROW + 32 + quad * 8];
      short8 fKi0 = *(const short8*)&sB[cbu + 2304 + krow * KROW + quad * 8];
      short8 fKi1 = *(const short8*)&sB[cbu + 2304 + krow * KROW + 32 + quad * 8];
      // chain-split: 4 independent 2-deep chains (A: d-low, B: d-high)
      f32x4 cSrA = {}, cSrB = {}, cSiA = {}, cSiB = {};
      cSrA = MFMA16(fKr0, fQr[0], cSrA);
      cSrB = MFMA16(fKr1, fQr[1], cSrB);
      cSiA = MFMA16(fKi0, fQr[0], cSiA);
      cSiB = MFMA16(fKi1, fQr[1], cSiB);
      cSrA = MFMA16(fKi0, fQn[0], cSrA);    // ki * (-qi)
      cSrB = MFMA16(fKi1, fQn[1], cSrB);
      cSiA = MFMA16(fKr0, fQi[0], cSiA);
      cSiB = MFMA16(fKr1, fQi[1], cSiB);
      f32x4 cSr = cSrA + cSrB;
      f32x4 cSi = cSiA + cSiB;
      // temperature /8 cancels in the min-max norm (scale-invariant)
      unsigned pd[4], p2[4], ud[4], u2[4];
#pragma unroll
      for (int r = 0; r < 4; ++r) {
        float sr = cSr[r], si = cSi[r];
        float t2 = sr * sr + si * si;
        float rq = __builtin_amdgcn_rsqf(t2);
        mn2 = fminf(mn2, t2);
        mx2 = fmaxf(mx2, t2);
        float ur = sr * rq, ui = si * rq;
        pd[r] = cvtpk(sr, si);               // pair (re, im)
        p2[r] = cvtpk(si, -sr);              // pair (im, -re): dual-P for Im path
        ud[r] = cvtpk(ur, ui);               // unit phase
        u2[r] = cvtpk(ui, -ur);
      }
      short8 fP, fP2, fU, fU2;
      __builtin_memcpy(&fP, pd, 16);
      __builtin_memcpy(&fP2, p2, 16);
      __builtin_memcpy(&fU, ud, 16);
      __builtin_memcpy(&fU2, u2, 16);

      // ---- PV for this ks half: all four accs consume the SAME vre frag ----
      //  Re: (pr,pi).(vr,-vi) = pr*vr - pi*vi;  Im: (pi,-pr).(vr,-vi) = pi*vr + pr*vi
#pragma unroll
      for (int dt = 0; dt < 4; ++dt) {
        const unsigned* vrow =
            (const unsigned*)sB + cbd + 2304 + (dt * 16 + m) * 36 + ks * 16 + quad * 4;
        short8 vre = *(const short8*)vrow;   // (vr,-vi) interleaved
        aAr[dt] = MFMA16(fP, vre, aAr[dt]);
        aAi[dt] = MFMA16(fP2, vre, aAi[dt]);
        aUr[dt] = MFMA16(fU, vre, aUr[dt]);
        aUi[dt] = MFMA16(fU2, vre, aUi[dt]);
      }
    }
    __syncthreads();   // drains glds (vmcnt) + LDS reads; buf swap is safe
  }

  // ---- reduce mn/mx across the 4 quads sharing q=m; redistribute via shfl; epilogue ----
#pragma unroll
  for (int mask = 16; mask < 64; mask <<= 1) {
    mn2 = fminf(mn2, __shfl_xor(mn2, mask, 64));
    mx2 = fmaxf(mx2, __shfl_xor(mx2, mask, 64));
  }
  const float mnv = sqrtf(mn2);
  const float invv = 1.0f / (sqrtf(mx2) - mnv);
  const int qbase = qt * 64 + wave * 16 + quad * 4;
#pragma unroll
  for (int r = 0; r < 4; ++r) {
    const int src = quad * 4 + r;            // lane (quad0, m=src) holds stats for this q
    const float mnr = __shfl(mnv, src, 64);
    const float ivr = __shfl(invv, src, 64);
#pragma unroll
    for (int dt = 0; dt < 4; ++dt) {
      const int d = dt * 16 + m;
      size_t o = base + (size_t)(qbase + r) * D + d;
      gout[o] = (aAr[dt][r] - mnr * aUr[dt][r]) * ivr;
      gout[HALF + o] = (aAi[dt][r] - mnr * aUi[dt][r]) * ivr;
    }
  }
}

// ---------------- fp32 fallback (used only if ws too small) ----------------
constexpr int QT = 32, KT = 32;
constexpr int DP = D + 4;
constexpr int KP = KT + 1;

#define CDOT4(SR, SI, AR, AI, BR, BI)                              \
  SR += AR.x*BR.x + AR.y*BR.y + AR.z*BR.z + AR.w*BR.w              \
      - AI.x*BI.x - AI.y*BI.y - AI.z*BI.z - AI.w*BI.w;             \
  SI += AR.x*BI.x + AR.y*BI.y + AR.z*BI.z + AR.w*BI.w              \
      + AI.x*BR.x + AI.y*BR.y + AI.z*BR.z + AI.w*BR.w;

__global__ __launch_bounds__(256, 2)
void cvattn_fallback(const float* __restrict__ gq_r, const float* __restrict__ gq_i,
                     const float* __restrict__ gk_r, const float* __restrict__ gk_i,
                     const float* __restrict__ gv_r, const float* __restrict__ gv_i,
                     float* __restrict__ gout) {
  __shared__ float qs_r[QT][DP], qs_i[QT][DP];
  __shared__ float ks_r[KT][DP], ks_i[KT][DP];
  __shared__ float vs_r[KT][DP], vs_i[KT][DP];
  __shared__ float sc_r[QT][KP], sc_i[QT][KP], sc_m[QT][KP];
  const int t = threadIdx.x;
  const int qt2 = blockIdx.x, bh = blockIdx.y;
  const size_t base = (size_t)bh * (S * D);
  {
    const float* qr_p = gq_r + base + (size_t)qt2 * QT * D;
    const float* qi_p = gq_i + base + (size_t)qt2 * QT * D;
#pragma unroll
    for (int i = 0; i < 2; ++i) {
      int e = (t + i * 256) * 4;
      int row = e >> 6, col = e & 63;
      *(float4*)&qs_r[row][col] = *(const float4*)(qr_p + e);
      *(float4*)&qs_i[row][col] = *(const float4*)(qi_p + e);
    }
  }
  const int q0 = (t >> 4) * 2, k0 = (t & 15) * 2;
  const int rB = t >> 3, dc = (t & 7) * 8;
  float Ar[8] = {}, Ai[8] = {}, Ur[8] = {}, Ui[8] = {};
  float mn = 3.4e38f, mx = 0.0f;
  for (int kb = 0; kb < S / KT; ++kb) {
    __syncthreads();
    {
      const float* kr_p = gk_r + base + (size_t)kb * KT * D;
      const float* ki_p = gk_i + base + (size_t)kb * KT * D;
      const float* vr_p = gv_r + base + (size_t)kb * KT * D;
      const float* vi_p = gv_i + base + (size_t)kb * KT * D;
#pragma unroll
      for (int i = 0; i < 2; ++i) {
        int e = (t + i * 256) * 4;
        int row = e >> 6, col = e & 63;
        *(float4*)&ks_r[row][col] = *(const float4*)(kr_p + e);
        *(float4*)&ks_i[row][col] = *(const float4*)(ki_p + e);
        *(float4*)&vs_r[row][col] = *(const float4*)(vr_p + e);
        *(float4*)&vs_i[row][col] = *(const float4*)(vi_p + e);
      }
    }
    __syncthreads();
    {
      float s00r=0.f,s00i=0.f,s01r=0.f,s01i=0.f;
      float s10r=0.f,s10i=0.f,s11r=0.f,s11i=0.f;
#pragma unroll
      for (int d = 0; d < D; d += 4) {
        float4 a0r = *(const float4*)&qs_r[q0  ][d];
        float4 a0i = *(const float4*)&qs_i[q0  ][d];
        float4 a1r = *(const float4*)&qs_r[q0+1][d];
        float4 a1i = *(const float4*)&qs_i[q0+1][d];
        float4 b0r = *(const float4*)&ks_r[k0  ][d];
        float4 b0i = *(const float4*)&ks_i[k0  ][d];
        float4 b1r = *(const float4*)&ks_r[k0+1][d];
        float4 b1i = *(const float4*)&ks_i[k0+1][d];
        CDOT4(s00r, s00i, a0r, a0i, b0r, b0i);
        CDOT4(s01r, s01i, a0r, a0i, b1r, b1i);
        CDOT4(s10r, s10i, a1r, a1i, b0r, b0i);
        CDOT4(s11r, s11i, a1r, a1i, b1r, b1i);
      }
      s00r *= 0.125f; s00i *= 0.125f; s01r *= 0.125f; s01i *= 0.125f;
      s10r *= 0.125f; s10i *= 0.125f; s11r *= 0.125f; s11i *= 0.125f;
      sc_r[q0  ][k0  ] = s00r; sc_i[q0  ][k0  ] = s00i;
      sc_m[q0  ][k0  ] = sqrtf(s00r*s00r + s00i*s00i);
      sc_r[q0  ][k0+1] = s01r; sc_i[q0  ][k0+1] = s01i;
      sc_m[q0  ][k0+1] = sqrtf(s01r*s01r + s01i*s01i);
      sc_r[q0+1][k0  ] = s10r; sc_i[q0+1][k0  ] = s10i;
      sc_m[q0+1][k0  ] = sqrtf(s10r*s10r + s10i*s10i);
      sc_r[q0+1][k0+1] = s11r; sc_i[q0+1][k0+1] = s11i;
      sc_m[q0+1][k0+1] = sqrtf(s11r*s11r + s11i*s11i);
    }
    __syncthreads();
#pragma unroll 8
    for (int k = 0; k < KT; ++k) {
      float sr = sc_r[rB][k], si = sc_i[rB][k], mg = sc_m[rB][k];
      mn = fminf(mn, mg); mx = fmaxf(mx, mg);
      float inv = 1.0f / mg;
      float ur = sr * inv, ui = si * inv;
      float vr[8], vi[8];
      *(float4*)&vr[0] = *(const float4*)&vs_r[k][dc];
      *(float4*)&vr[4] = *(const float4*)&vs_r[k][dc + 4];
      *(float4*)&vi[0] = *(const float4*)&vs_i[k][dc];
      *(float4*)&vi[4] = *(const float4*)&vs_i[k][dc + 4];
#pragma unroll
      for (int j = 0; j < 8; ++j) {
        Ar[j] += sr * vr[j] - si * vi[j];
        Ai[j] += sr * vi[j] + si * vr[j];
        Ur[j] += ur * vr[j] - ui * vi[j];
        Ui[j] += ur * vi[j] + ui * vr[j];
      }
    }
  }
  float invspan = 1.0f / (mx - mn);
  float outr[8], outi[8];
#pragma unroll
  for (int j = 0; j < 8; ++j) {
    outr[j] = (Ar[j] - mn * Ur[j]) * invspan;
    outi[j] = (Ai[j] - mn * Ui[j]) * invspan;
  }
  size_t o = base + (size_t)(qt2 * QT + rB) * D + dc;
  *(float4*)(gout + o)            = *(float4*)&outr[0];
  *(float4*)(gout + o + 4)        = *(float4*)&outr[4];
  *(float4*)(gout + HALF + o)     = *(float4*)&outi[0];
  *(float4*)(gout + HALF + o + 4) = *(float4*)&outi[4];
}

extern "C" void kernel_launch(void* const* d_in, const int* in_sizes, int n_in,
                              void* d_out, int out_size, void* d_ws, size_t ws_size,
                              hipStream_t stream) {
  if (ws_size >= WS_NEED) {
    prepass_kernel<<<dim3(BH * 32 / 2), 256, 0, stream>>>(
        (const float*)d_in[2], (const float*)d_in[3],
        (const float*)d_in[4], (const float*)d_in[5], (ushort_t*)d_ws);
    cvattn_mfma<<<dim3(S / 64 * BH), 256, 0, stream>>>(
        (const float*)d_in[0], (const float*)d_in[1],
        (const ushort_t*)d_ws, (float*)d_out);
  } else {
    cvattn_fallback<<<dim3(S / QT, BH), 256, 0, stream>>>(
        (const float*)d_in[0], (const float*)d_in[1],
        (const float*)d_in[2], (const float*)d_in[3],
        (const float*)d_in[4], (const float*)d_in[5], (float*)d_out);
  }
}

// Round 12
// 242.102 us; speedup vs baseline: 1.3621x; 1.3621x over previous
//
#include <hip/hip_runtime.h>
#include <math.h>

typedef unsigned short ushort_t;
typedef __attribute__((ext_vector_type(8))) short short8;   // 8 bf16 = 4 VGPR (MFMA A/B frag)
typedef __attribute__((ext_vector_type(4))) float f32x4;    // MFMA C/D frag
typedef __attribute__((ext_vector_type(4))) int int4v;

constexpr int S = 1024, D = 64, BH = 64;
constexpr int HALF = BH * S * D;          // imag offset in output
constexpr int KROW = 72;                  // ush row stride, K tiles (rows=s, cols=d)
constexpr int VROW = 72;                  // ush row stride, interleaved V^T (rows=d, cols=k'=2s+c)
constexpr int TILE_USH = 2 * 32 * KROW + 64 * VROW;  // 4608 + 4608 = 9216 ush = 18432 B
constexpr int TILE_B = TILE_USH * 2;                 // 18432 B
constexpr size_t WS_NEED = (size_t)BH * 32 * TILE_B; // 37.7 MB (< 39.8 MB cap)

#define MFMA16(a, b, c) __builtin_amdgcn_mfma_f32_16x16x32_bf16(a, b, c, 0, 0, 0)

// ---- packed fp32->bf16 (RNE): lo=bf16(a), hi=bf16(b) ----
// R1/R5 lesson: raw `v_cvt_pk_bf16_f32` inline asm does NOT behave as a two-source
// pack on this toolchain. The __bf16-cast form is correct; never asm this.
__device__ __forceinline__ unsigned cvtpk(float a, float b) {
  __bf16 la = (__bf16)a, lb = (__bf16)b;
  unsigned short lo, hi;
  __builtin_memcpy(&lo, &la, 2);
  __builtin_memcpy(&hi, &lb, 2);
  return (unsigned)lo | ((unsigned)hi << 16);
}

__device__ __forceinline__ int4v pack8(float4 a, float4 b) {  // 8 fp32 -> 8 bf16 in 16B
  int4v r;
  r.x = (int)cvtpk(a.x, a.y);
  r.y = (int)cvtpk(a.z, a.w);
  r.z = (int)cvtpk(b.x, b.y);
  r.w = (int)cvtpk(b.z, b.w);
  return r;
}

// async global->LDS staging of one 18432 B tile (linear both sides), 512 threads.
__device__ __forceinline__ void stage_tile512(const ushort_t* __restrict__ g,
                                              char* l, int t) {
#pragma unroll
  for (int i = 0; i < 3; ++i) {
    const int idx = i * 512 + t;
    if (idx < TILE_B / 16) {
      __builtin_amdgcn_global_load_lds(
          (const __attribute__((address_space(1))) unsigned*)(g) + idx * 4,
          (__attribute__((address_space(3))) unsigned*)(l) + idx * 4, 16, 0, 0);
    }
  }
}

// ---------------- prepass: K classic bf16; V^T complex-interleaved (vr,-vi) --------------
// R9 lesson: total - dispatch is a CONSTANT ~115us fixed harness overhead regardless of
// kernel count -> prepass is near its roofline. R8 version, unchanged.
__global__ __launch_bounds__(256)
void prepass_kernel(const float* __restrict__ kr, const float* __restrict__ ki,
                    const float* __restrict__ vr, const float* __restrict__ vi,
                    ushort_t* __restrict__ ws) {
  __shared__ float svr[32 * 72], svi[32 * 72];
  const int t = threadIdx.x;
  const int k = t >> 3, d0 = (t & 7) * 8;
  const int dT = t >> 2, k0 = (t & 3) * 8;

  for (int it = 0; it < 2; ++it) {
    const int tile = blockIdx.x * 2 + it;
    const size_t gbase = (size_t)tile * (32 * D);
    ushort_t* wst = ws + (size_t)tile * TILE_USH;
    {
      float4 a = *(const float4*)(kr + gbase + k * D + d0);
      float4 b = *(const float4*)(kr + gbase + k * D + d0 + 4);
      *(int4v*)(wst + k * KROW + d0) = pack8(a, b);
    }
    {
      float4 a = *(const float4*)(ki + gbase + k * D + d0);
      float4 b = *(const float4*)(ki + gbase + k * D + d0 + 4);
      *(int4v*)(wst + 2304 + k * KROW + d0) = pack8(a, b);
    }
    {
      float4 a = *(const float4*)(vr + gbase + k * D + d0);
      float4 b = *(const float4*)(vr + gbase + k * D + d0 + 4);
      *(float4*)&svr[k * 72 + d0] = a;
      *(float4*)&svr[k * 72 + d0 + 4] = b;
      float4 c = *(const float4*)(vi + gbase + k * D + d0);
      float4 d = *(const float4*)(vi + gbase + k * D + d0 + 4);
      *(float4*)&svi[k * 72 + d0] = c;
      *(float4*)&svi[k * 72 + d0 + 4] = d;
    }
    __syncthreads();
    {
      unsigned dws[8];
#pragma unroll
      for (int j = 0; j < 8; ++j) {
        int s = k0 + j;
        dws[j] = cvtpk(svr[s * 72 + dT], -svi[s * 72 + dT]);  // pair (vr, -vi)
      }
      ushort_t* dst = wst + 4608 + dT * VROW + 2 * k0;
      *(int4v*)dst = *(int4v*)&dws[0];
      *(int4v*)(dst + 8) = *(int4v*)&dws[4];
    }
    __syncthreads();
  }
}

// ---------------- main MFMA kernel: 128 q-rows/block, 8 waves, 4 blocks/CU ----------------
// Round 12: occupancy 16 -> 32 waves/CU. R10 (phase batching) and R11 (chain split ->
// VGPR spill, FETCH 46->455MB) prove intra-wave ILP surgery is done; the remaining
// lever is wave count. Per-wave code is BYTE-IDENTICAL to R8 (VGPR 64, zero spill);
// block is 512 threads (8 waves over 128 q-rows), still 4 blocks/CU by LDS, but now
// 8 waves/SIMD (64 VGPR x 8 = 512 = full RF). Bonus: each staged tile feeds 8 waves
// -> ws re-fetch halves.
__global__ __launch_bounds__(512, 4)
void cvattn_mfma(const float* __restrict__ gq_r, const float* __restrict__ gq_i,
                 const ushort_t* __restrict__ ws, float* __restrict__ gout) {
  __shared__ __attribute__((aligned(16))) char smem[2 * 18432];
  ushort_t* sB = (ushort_t*)smem;
  const int t = threadIdx.x;
  const int lane = t & 63, wave = t >> 6;    // wave 0..7
  const int m = lane & 15, quad = lane >> 4;

  // XCD-aware block mapping: all 8 q-tiles of one bh share id%8 -> same XCD L2.
  const int id = blockIdx.x;                 // 0..511
  const int bh = (id & 7) * 8 + ((id >> 3) & 7);
  const int qt = id >> 6;                    // 0..7 (128 q-rows each)
  const size_t base = (size_t)bh * (S * D);

  // ---- Q fragments straight from global (one-time, uncoalesced-but-small) ----
  short8 fQr[2], fQi[2], fQn[2];   // [dc]; fQn = -fQi (loop-invariant)
  {
    const int row = qt * 128 + wave * 16 + m;
#pragma unroll
    for (int dc = 0; dc < 2; ++dc) {
      const int d = dc * 32 + quad * 8;
      const float* pr = gq_r + base + (size_t)row * D + d;
      const float* pi = gq_i + base + (size_t)row * D + d;
      int4v vr_ = pack8(*(const float4*)pr, *(const float4*)(pr + 4));
      int4v vi_ = pack8(*(const float4*)pi, *(const float4*)(pi + 4));
      __builtin_memcpy(&fQr[dc], &vr_, 16);
      __builtin_memcpy(&fQi[dc], &vi_, 16);
      fQn[dc] = fQi[dc] ^ (short)0x8000;
    }
  }

  f32x4 aAr[4] = {}, aAi[4] = {}, aUr[4] = {}, aUi[4] = {};
  float mn2 = 1e30f, mx2 = 0.f;              // per-lane stats of |s|^2, q = m

  const ushort_t* wsrc = ws + (size_t)bh * 32 * TILE_USH;

  // ---- prologue: tile0 -> buf0 (async), drain at barrier ----
  stage_tile512(wsrc, smem, t);
  __syncthreads();

  for (int kb = 0; kb < 32; ++kb) {
    const int cur = kb & 1;
    const int cbu = cur * 9216;        // ush offset of current buffer
    const int cbd = cur * 4608;        // dw offset

    // issue next tile's async loads first; they complete under this iter's compute
    if (kb + 1 < 32)
      stage_tile512(wsrc + (size_t)(kb + 1) * TILE_USH, smem + (cur ^ 1) * 18432, t);

    // ---- swapped QK^T (mfma(K,Q)): lane(m,quad) gets S[q=m][k=ks*16+quad*4+r],
    //      which IS the PV A-frag layout -> P/U built in-lane, no LDS round-trip.
#pragma unroll
    for (int ks = 0; ks < 2; ++ks) {
      const int krow = ks * 16 + m;
      short8 fKr0 = *(const short8*)&sB[cbu + krow * KROW + quad * 8];
      short8 fKr1 = *(const short8*)&sB[cbu + krow * KROW + 32 + quad * 8];
      short8 fKi0 = *(const short8*)&sB[cbu + 2304 + krow * KROW + quad * 8];
      short8 fKi1 = *(const short8*)&sB[cbu + 2304 + krow * KROW + 32 + quad * 8];
      f32x4 cSr = {}, cSi = {};
      cSr = MFMA16(fKr0, fQr[0], cSr);
      cSr = MFMA16(fKr1, fQr[1], cSr);
      cSr = MFMA16(fKi0, fQn[0], cSr);      // ki * (-qi)
      cSr = MFMA16(fKi1, fQn[1], cSr);
      cSi = MFMA16(fKi0, fQr[0], cSi);
      cSi = MFMA16(fKi1, fQr[1], cSi);
      cSi = MFMA16(fKr0, fQi[0], cSi);
      cSi = MFMA16(fKr1, fQi[1], cSi);
      // temperature /8 cancels in the min-max norm (scale-invariant)
      unsigned pd[4], p2[4], ud[4], u2[4];
#pragma unroll
      for (int r = 0; r < 4; ++r) {
        float sr = cSr[r], si = cSi[r];
        float t2 = sr * sr + si * si;
        float rq = __builtin_amdgcn_rsqf(t2);
        mn2 = fminf(mn2, t2);
        mx2 = fmaxf(mx2, t2);
        float ur = sr * rq, ui = si * rq;
        pd[r] = cvtpk(sr, si);               // pair (re, im)
        p2[r] = cvtpk(si, -sr);              // pair (im, -re): dual-P for Im path
        ud[r] = cvtpk(ur, ui);               // unit phase
        u2[r] = cvtpk(ui, -ur);
      }
      short8 fP, fP2, fU, fU2;
      __builtin_memcpy(&fP, pd, 16);
      __builtin_memcpy(&fP2, p2, 16);
      __builtin_memcpy(&fU, ud, 16);
      __builtin_memcpy(&fU2, u2, 16);

      // ---- PV for this ks half: all four accs consume the SAME vre frag ----
      //  Re: (pr,pi).(vr,-vi) = pr*vr - pi*vi;  Im: (pi,-pr).(vr,-vi) = pi*vr + pr*vi
#pragma unroll
      for (int dt = 0; dt < 4; ++dt) {
        const unsigned* vrow =
            (const unsigned*)sB + cbd + 2304 + (dt * 16 + m) * 36 + ks * 16 + quad * 4;
        short8 vre = *(const short8*)vrow;   // (vr,-vi) interleaved
        aAr[dt] = MFMA16(fP, vre, aAr[dt]);
        aAi[dt] = MFMA16(fP2, vre, aAi[dt]);
        aUr[dt] = MFMA16(fU, vre, aUr[dt]);
        aUi[dt] = MFMA16(fU2, vre, aUi[dt]);
      }
    }
    __syncthreads();   // drains glds (vmcnt) + LDS reads; buf swap is safe
  }

  // ---- reduce mn/mx across the 4 quads sharing q=m; redistribute via shfl; epilogue ----
#pragma unroll
  for (int mask = 16; mask < 64; mask <<= 1) {
    mn2 = fminf(mn2, __shfl_xor(mn2, mask, 64));
    mx2 = fmaxf(mx2, __shfl_xor(mx2, mask, 64));
  }
  const float mnv = sqrtf(mn2);
  const float invv = 1.0f / (sqrtf(mx2) - mnv);
  const int qbase = qt * 128 + wave * 16 + quad * 4;
#pragma unroll
  for (int r = 0; r < 4; ++r) {
    const int src = quad * 4 + r;            // lane (quad0, m=src) holds stats for this q
    const float mnr = __shfl(mnv, src, 64);
    const float ivr = __shfl(invv, src, 64);
#pragma unroll
    for (int dt = 0; dt < 4; ++dt) {
      const int d = dt * 16 + m;
      size_t o = base + (size_t)(qbase + r) * D + d;
      gout[o] = (aAr[dt][r] - mnr * aUr[dt][r]) * ivr;
      gout[HALF + o] = (aAi[dt][r] - mnr * aUi[dt][r]) * ivr;
    }
  }
}

// ---------------- fp32 fallback (used only if ws too small) ----------------
constexpr int QT = 32, KT = 32;
constexpr int DP = D + 4;
constexpr int KP = KT + 1;

#define CDOT4(SR, SI, AR, AI, BR, BI)                              \
  SR += AR.x*BR.x + AR.y*BR.y + AR.z*BR.z + AR.w*BR.w              \
      - AI.x*BI.x - AI.y*BI.y - AI.z*BI.z - AI.w*BI.w;             \
  SI += AR.x*BI.x + AR.y*BI.y + AR.z*BI.z + AR.w*BI.w              \
      + AI.x*BR.x + AI.y*BR.y + AI.z*BR.z + AI.w*BR.w;

__global__ __launch_bounds__(256, 2)
void cvattn_fallback(const float* __restrict__ gq_r, const float* __restrict__ gq_i,
                     const float* __restrict__ gk_r, const float* __restrict__ gk_i,
                     const float* __restrict__ gv_r, const float* __restrict__ gv_i,
                     float* __restrict__ gout) {
  __shared__ float qs_r[QT][DP], qs_i[QT][DP];
  __shared__ float ks_r[KT][DP], ks_i[KT][DP];
  __shared__ float vs_r[KT][DP], vs_i[KT][DP];
  __shared__ float sc_r[QT][KP], sc_i[QT][KP], sc_m[QT][KP];
  const int t = threadIdx.x;
  const int qt2 = blockIdx.x, bh = blockIdx.y;
  const size_t base = (size_t)bh * (S * D);
  {
    const float* qr_p = gq_r + base + (size_t)qt2 * QT * D;
    const float* qi_p = gq_i + base + (size_t)qt2 * QT * D;
#pragma unroll
    for (int i = 0; i < 2; ++i) {
      int e = (t + i * 256) * 4;
      int row = e >> 6, col = e & 63;
      *(float4*)&qs_r[row][col] = *(const float4*)(qr_p + e);
      *(float4*)&qs_i[row][col] = *(const float4*)(qi_p + e);
    }
  }
  const int q0 = (t >> 4) * 2, k0 = (t & 15) * 2;
  const int rB = t >> 3, dc = (t & 7) * 8;
  float Ar[8] = {}, Ai[8] = {}, Ur[8] = {}, Ui[8] = {};
  float mn = 3.4e38f, mx = 0.0f;
  for (int kb = 0; kb < S / KT; ++kb) {
    __syncthreads();
    {
      const float* kr_p = gk_r + base + (size_t)kb * KT * D;
      const float* ki_p = gk_i + base + (size_t)kb * KT * D;
      const float* vr_p = gv_r + base + (size_t)kb * KT * D;
      const float* vi_p = gv_i + base + (size_t)kb * KT * D;
#pragma unroll
      for (int i = 0; i < 2; ++i) {
        int e = (t + i * 256) * 4;
        int row = e >> 6, col = e & 63;
        *(float4*)&ks_r[row][col] = *(const float4*)(kr_p + e);
        *(float4*)&ks_i[row][col] = *(const float4*)(ki_p + e);
        *(float4*)&vs_r[row][col] = *(const float4*)(vr_p + e);
        *(float4*)&vs_i[row][col] = *(const float4*)(vi_p + e);
      }
    }
    __syncthreads();
    {
      float s00r=0.f,s00i=0.f,s01r=0.f,s01i=0.f;
      float s10r=0.f,s10i=0.f,s11r=0.f,s11i=0.f;
#pragma unroll
      for (int d = 0; d < D; d += 4) {
        float4 a0r = *(const float4*)&qs_r[q0  ][d];
        float4 a0i = *(const float4*)&qs_i[q0  ][d];
        float4 a1r = *(const float4*)&qs_r[q0+1][d];
        float4 a1i = *(const float4*)&qs_i[q0+1][d];
        float4 b0r = *(const float4*)&ks_r[k0  ][d];
        float4 b0i = *(const float4*)&ks_i[k0  ][d];
        float4 b1r = *(const float4*)&ks_r[k0+1][d];
        float4 b1i = *(const float4*)&ks_i[k0+1][d];
        CDOT4(s00r, s00i, a0r, a0i, b0r, b0i);
        CDOT4(s01r, s01i, a0r, a0i, b1r, b1i);
        CDOT4(s10r, s10i, a1r, a1i, b0r, b0i);
        CDOT4(s11r, s11i, a1r, a1i, b1r, b1i);
      }
      s00r *= 0.125f; s00i *= 0.125f; s01r *= 0.125f; s01i *= 0.125f;
      s10r *= 0.125f; s10i *= 0.125f; s11r *= 0.125f; s11i *= 0.125f;
      sc_r[q0  ][k0  ] = s00r; sc_i[q0  ][k0  ] = s00i;
      sc_m[q0  ][k0  ] = sqrtf(s00r*s00r + s00i*s00i);
      sc_r[q0  ][k0+1] = s01r; sc_i[q0  ][k0+1] = s01i;
      sc_m[q0  ][k0+1] = sqrtf(s01r*s01r + s01i*s01i);
      sc_r[q0+1][k0  ] = s10r; sc_i[q0+1][k0  ] = s10i;
      sc_m[q0+1][k0  ] = sqrtf(s10r*s10r + s10i*s10i);
      sc_r[q0+1][k0+1] = s11r; sc_i[q0+1][k0+1] = s11i;
      sc_m[q0+1][k0+1] = sqrtf(s11r*s11r + s11i*s11i);
    }
    __syncthreads();
#pragma unroll 8
    for (int k = 0; k < KT; ++k) {
      float sr = sc_r[rB][k], si = sc_i[rB][k], mg = sc_m[rB][k];
      mn = fminf(mn, mg); mx = fmaxf(mx, mg);
      float inv = 1.0f / mg;
      float ur = sr * inv, ui = si * inv;
      float vr[8], vi[8];
      *(float4*)&vr[0] = *(const float4*)&vs_r[k][dc];
      *(float4*)&vr[4] = *(const float4*)&vs_r[k][dc + 4];
      *(float4*)&vi[0] = *(const float4*)&vs_i[k][dc];
      *(float4*)&vi[4] = *(const float4*)&vs_i[k][dc + 4];
#pragma unroll
      for (int j = 0; j < 8; ++j) {
        Ar[j] += sr * vr[j] - si * vi[j];
        Ai[j] += sr * vi[j] + si * vr[j];
        Ur[j] += ur * vr[j] - ui * vi[j];
        Ui[j] += ur * vi[j] + ui * vr[j];
      }
    }
  }
  float invspan = 1.0f / (mx - mn);
  float outr[8], outi[8];
#pragma unroll
  for (int j = 0; j < 8; ++j) {
    outr[j] = (Ar[j] - mn * Ur[j]) * invspan;
    outi[j] = (Ai[j] - mn * Ui[j]) * invspan;
  }
  size_t o = base + (size_t)(qt2 * QT + rB) * D + dc;
  *(float4*)(gout + o)            = *(float4*)&outr[0];
  *(float4*)(gout + o + 4)        = *(float4*)&outr[4];
  *(float4*)(gout + HALF + o)     = *(float4*)&outi[0];
  *(float4*)(gout + HALF + o + 4) = *(float4*)&outi[4];
}

extern "C" void kernel_launch(void* const* d_in, const int* in_sizes, int n_in,
                              void* d_out, int out_size, void* d_ws, size_t ws_size,
                              hipStream_t stream) {
  if (ws_size >= WS_NEED) {
    prepass_kernel<<<dim3(BH * 32 / 2), 256, 0, stream>>>(
        (const float*)d_in[2], (const float*)d_in[3],
        (const float*)d_in[4], (const float*)d_in[5], (ushort_t*)d_ws);
    cvattn_mfma<<<dim3(S / 128 * BH), 512, 0, stream>>>(
        (const float*)d_in[0], (const float*)d_in[1],
        (const ushort_t*)d_ws, (float*)d_out);
  } else {
    cvattn_fallback<<<dim3(S / QT, BH), 256, 0, stream>>>(
        (const float*)d_in[0], (const float*)d_in[1],
        (const float*)d_in[2], (const float*)d_in[3],
        (const float*)d_in[4], (const float*)d_in[5], (float*)d_out);
  }
}